// Round 5
// baseline (100.771 us; speedup 1.0000x reference)
//
#include <hip/hip_runtime.h>
#include <math.h>

// The reference network is ENTIRELY LINEAR before log_softmax, so it
// collapses to logits[b,n] = b_cls[n] + <x[b], Wx[n]>, Wx: (10,3,32,32).
// Round-5: the two 3x3 full-correlation folds compose into ONE 5x5
// correlation applied to Wcls directly:
//   M[r1,r2]    = sum_f l1_f0[f,r1]*l2_f3[f,r2]
//   K[c,ij,r2]  = sum_r1 l1_f3[c,r1]*(l1_f1[i,r1]*l1_f2[j,r1])*M[r1,r2]
//   E[c,r2,u,v] = sum_{i+k=u, j+l=v} K[c,ij,r2]*(l2_f1[k,r2]*l2_f2[l,r2])
//   G[c,uv,f]   = sum_r2 E[c,r2,uv]*l2_f0[f,r2]            (3x25x32, 9.6KB)
//   Wx[n,c,H,W] = sum_{uv: 0<=H-u<28, 0<=W-v<28} sum_f
//                     G[c,uv,f] * Wcls[n, f*784+(H-u)*28+(W-v)]
// (the intermediate 30-wide bound is automatically enforced by the 28 bound)
// G is tiny (~60K FMA) -> computed REDUNDANTLY per block, so the whole
// precompute is ONE dispatch (no Wc3 intermediate, no second precomp).

// ---- K1: Wx (120 blocks x 256 thr, 1 output/thread; G built in LDS) ----
__global__ __launch_bounds__(256) void wx_kernel(
    const float* __restrict__ l1_f0, const float* __restrict__ l1_f1,
    const float* __restrict__ l1_f2, const float* __restrict__ l1_f3,
    const float* __restrict__ l2_f0, const float* __restrict__ l2_f1,
    const float* __restrict__ l2_f2, const float* __restrict__ l2_f3,
    const float* __restrict__ Wcls,
    float* __restrict__ Wx) {
    __shared__ float sM[256];        // [r1][r2]
    __shared__ float sK[432];        // [(c*9+ij)*16 + r2]
    __shared__ float sE[1200];       // [(c*25+uv)*16 + r2]
    __shared__ float sG[2400];       // [(c*25+uv)*32 + f]
    const int tid = threadIdx.x;

    // phase 1: M
    {
        int r1 = tid >> 4, r2 = tid & 15;
        float acc = 0.f;
#pragma unroll
        for (int f = 0; f < 32; ++f)
            acc += l1_f0[f * 16 + r1] * l2_f3[f * 16 + r2];
        sM[tid] = acc;
    }
    __syncthreads();
    // phase 2: K
    for (int t = tid; t < 432; t += 256) {
        int r2 = t & 15;
        int e = t >> 4;              // c*9 + ij
        int c = e / 9, ij = e - c * 9;
        int i = ij / 3, j = ij - i * 3;
        float acc = 0.f;
#pragma unroll
        for (int r1 = 0; r1 < 16; ++r1)
            acc += l1_f3[c * 16 + r1] * l1_f1[i * 16 + r1] * l1_f2[j * 16 + r1]
                 * sM[r1 * 16 + r2];
        sK[t] = acc;
    }
    __syncthreads();
    // phase 3: E (5x5 composition)
    for (int t = tid; t < 1200; t += 256) {
        int r2 = t & 15;
        int e = t >> 4;              // c*25 + uv
        int c = e / 25, uv = e - c * 25;
        int u = uv / 5, v = uv - u * 5;
        float acc = 0.f;
        int ilo = u > 2 ? u - 2 : 0, ihi = u < 2 ? u : 2;
        int jlo = v > 2 ? v - 2 : 0, jhi = v < 2 ? v : 2;
        for (int i = ilo; i <= ihi; ++i) {
            int k = u - i;
            for (int j = jlo; j <= jhi; ++j) {
                int l = v - j;
                acc += sK[(c * 9 + i * 3 + j) * 16 + r2]
                     * l2_f1[k * 16 + r2] * l2_f2[l * 16 + r2];
            }
        }
        sE[t] = acc;
    }
    __syncthreads();
    // phase 4: G
    for (int t = tid; t < 2400; t += 256) {
        int f = t & 31;
        int e = t >> 5;              // c*25 + uv
        float acc = 0.f;
#pragma unroll
        for (int r2 = 0; r2 < 16; ++r2)
            acc += sE[e * 16 + r2] * l2_f0[f * 16 + r2];
        sG[t] = acc;
    }
    __syncthreads();

    // phase 5: one Wx element per thread
    const int t = blockIdx.x * 256 + tid;      // 0..30719
    const int n = t / 3072;
    const int rem = t - n * 3072;
    const int c = rem >> 10;
    const int p = rem & 1023;
    const int H = p >> 5, W = p & 31;
    const float* wn = Wcls + n * 25088;
    float acc = 0.f;
#pragma unroll
    for (int u = 0; u < 5; ++u) {
        int hh = H - u;
        if (hh < 0 || hh >= 28) continue;
#pragma unroll
        for (int v = 0; v < 5; ++v) {
            int ww = W - v;
            if (ww < 0 || ww >= 28) continue;
            const float* wp = wn + hh * 28 + ww;
            const float* gp = &sG[(c * 25 + u * 5 + v) * 32];
#pragma unroll
            for (int f = 0; f < 32; ++f)
                acc += gp[f] * wp[f * 784];
        }
    }
    Wx[t] = acc;   // layout n*3072 + c*1024 + H*32 + W (matches x)
}

// ---- K2: logits = x . Wx^T + b, then log_softmax. One block per image ----
__global__ __launch_bounds__(256) void cls_kernel(
    const float* __restrict__ x, const float* __restrict__ Wx,
    const float* __restrict__ b_cls, float* __restrict__ out) {
    __shared__ float sred[4][10];
    __shared__ float slog[10];
    const int tid = threadIdx.x;
    const int b = blockIdx.x;
    const float4* xb = (const float4*)(x + b * 3072);
    const float4* wx4 = (const float4*)Wx;

    float acc[10];
#pragma unroll
    for (int n = 0; n < 10; ++n) acc[n] = 0.f;
#pragma unroll
    for (int k = 0; k < 3; ++k) {
        const int idx = tid + k * 256;      // 0..767 float4 chunks
        float4 xv = xb[idx];
#pragma unroll
        for (int n = 0; n < 10; ++n) {
            float4 wv = wx4[n * 768 + idx];
            acc[n] += xv.x * wv.x + xv.y * wv.y + xv.z * wv.z + xv.w * wv.w;
        }
    }

    const int lane = tid & 63, wid = tid >> 6;
#pragma unroll
    for (int n = 0; n < 10; ++n) {
        float v = acc[n];
        for (int off = 32; off > 0; off >>= 1)
            v += __shfl_down(v, off, 64);
        if (lane == 0) sred[wid][n] = v;
    }
    __syncthreads();
    if (tid < 10) {
        slog[tid] = b_cls[tid] + sred[0][tid] + sred[1][tid]
                  + sred[2][tid] + sred[3][tid];
    }
    __syncthreads();
    if (tid < 10) {
        float m = -1e30f;
#pragma unroll
        for (int n = 0; n < 10; ++n) m = fmaxf(m, slog[n]);
        float ssum = 0.f;
#pragma unroll
        for (int n = 0; n < 10; ++n) ssum += expf(slog[n] - m);
        out[b * 10 + tid] = slog[tid] - m - logf(ssum);
    }
}

extern "C" void kernel_launch(void* const* d_in, const int* in_sizes, int n_in,
                              void* d_out, int out_size, void* d_ws, size_t ws_size,
                              hipStream_t stream) {
    const float* x     = (const float*)d_in[0];
    const float* l1_f0 = (const float*)d_in[1];
    const float* l1_f1 = (const float*)d_in[2];
    const float* l1_f2 = (const float*)d_in[3];
    const float* l1_f3 = (const float*)d_in[4];
    const float* l2_f0 = (const float*)d_in[5];
    const float* l2_f1 = (const float*)d_in[6];
    const float* l2_f2 = (const float*)d_in[7];
    const float* l2_f3 = (const float*)d_in[8];
    const float* Wcls  = (const float*)d_in[9];
    const float* bcls  = (const float*)d_in[10];
    float* out = (float*)d_out;

    float* Wx = (float*)d_ws;          // 10*3*1024 = 30720 floats (120 KB)

    wx_kernel<<<dim3(120), dim3(256), 0, stream>>>(
        l1_f0, l1_f1, l1_f2, l1_f3, l2_f0, l2_f1, l2_f2, l2_f3, Wcls, Wx);
    cls_kernel<<<dim3(512), dim3(256), 0, stream>>>(x, Wx, bcls, out);
}